// Round 9
// baseline (985.428 us; speedup 1.0000x reference)
//
#include <hip/hip_runtime.h>

// ---------------------------------------------------------------------------
// LightGCN propagation: out = normalize(mean(emb, A emb, A^2 emb, A^3 emb))
// for two graphs (mashup: 100k nodes / 3.2M edges, api: 50k / 1.6M), D=64.
//
// Round-8 = round-7 structure + COL-CHUNK-ORDERED CSR:
//  - build key = row*NC + chunk(col), chunk slice ~2MB of fp16 x (mashup
//    NC=7, api NC=4). Row segments stay contiguous (SpMM unchanged), but
//    edges within a row are column-chunk-sorted -> co-resident waves sweep
//    chunks in near-lockstep, so gathers concentrate in an L2-resident
//    slice (L2 hits instead of LLC round-trips). NO per-chunk dispatches,
//    NO y32 re-sweeps (round-6's mistake).
//  - per-key kpos aliases buf0h (build precedes SpMM); only per-row bounds
//    (row_ptr) persist. ws = 64.6MB < proven 65.2MB.
//  - Merged hist/scatter (XCD row-partitioned) + quad-edge SpMM from r7.
// ---------------------------------------------------------------------------

#define EMB_DIM 64
#define UNR 8
typedef unsigned long long ull;
typedef int v4i __attribute__((ext_vector_type(4)));

static inline int cdiv(long long a, long long b) { return (int)((a + b - 1) / b); }

// ----------------------------- CSR build -----------------------------------

__global__ void k_zero_i(int* __restrict__ p, int n) {
    int i = blockIdx.x * blockDim.x + threadIdx.x;
    if (i < n) p[i] = 0;
}

// merged key histogram: key = row*NC + chunk(col), 4 edges per thread.
__global__ void k_histk2(const int* __restrict__ rm, const int* __restrict__ cm,
                         int nem, int NCm, unsigned cmulm, int* __restrict__ km,
                         const int* __restrict__ ra, const int* __restrict__ ca,
                         int nea, int NCa, unsigned cmula, int* __restrict__ ka) {
    int nm4 = nem >> 2, na4 = nea >> 2;
    int i = blockIdx.x * blockDim.x + threadIdx.x;
    if (i < nm4) {
        v4i r = __builtin_nontemporal_load((const v4i*)rm + i);
        v4i c = __builtin_nontemporal_load((const v4i*)cm + i);
        atomicAdd(&km[r.x * NCm + (int)(((unsigned)c.x * cmulm) >> 16)], 1);
        atomicAdd(&km[r.y * NCm + (int)(((unsigned)c.y * cmulm) >> 16)], 1);
        atomicAdd(&km[r.z * NCm + (int)(((unsigned)c.z * cmulm) >> 16)], 1);
        atomicAdd(&km[r.w * NCm + (int)(((unsigned)c.w * cmulm) >> 16)], 1);
    } else if (i < nm4 + na4) {
        int ii = i - nm4;
        v4i r = __builtin_nontemporal_load((const v4i*)ra + ii);
        v4i c = __builtin_nontemporal_load((const v4i*)ca + ii);
        atomicAdd(&ka[r.x * NCa + (int)(((unsigned)c.x * cmula) >> 16)], 1);
        atomicAdd(&ka[r.y * NCa + (int)(((unsigned)c.y * cmula) >> 16)], 1);
        atomicAdd(&ka[r.z * NCa + (int)(((unsigned)c.z * cmula) >> 16)], 1);
        atomicAdd(&ka[r.w * NCa + (int)(((unsigned)c.w * cmula) >> 16)], 1);
    } else if (i == nm4 + na4) {
        for (int t = nm4 << 2; t < nem; ++t)
            atomicAdd(&km[rm[t] * NCm +
                          (int)(((unsigned)cm[t] * cmulm) >> 16)], 1);
        for (int t = na4 << 2; t < nea; ++t)
            atomicAdd(&ka[ra[t] * NCa +
                          (int)(((unsigned)ca[t] * cmula) >> 16)], 1);
    }
}

#define SCAN_B 256
#define SCAN_E 1024
// in-place safe: each thread reads its 4 elems before any write.
__global__ void k_scan1(const int* __restrict__ in, int n,
                        int* __restrict__ out, int* __restrict__ bsums) {
    __shared__ int lds[SCAN_B];
    int t = threadIdx.x;
    int base = blockIdx.x * SCAN_E + t * 4;
    int v[4];
    int s = 0;
#pragma unroll
    for (int j = 0; j < 4; ++j) {
        v[j] = (base + j < n) ? in[base + j] : 0;
        s += v[j];
    }
    lds[t] = s;
    __syncthreads();
    for (int off = 1; off < SCAN_B; off <<= 1) {
        int x = (t >= off) ? lds[t - off] : 0;
        __syncthreads();
        lds[t] += x;
        __syncthreads();
    }
    int run = lds[t] - s;
    if (t == SCAN_B - 1) bsums[blockIdx.x] = lds[t];
#pragma unroll
    for (int j = 0; j < 4; ++j) {
        if (base + j < n) out[base + j] = run;
        run += v[j];
    }
}

__global__ void k_scan2(int* __restrict__ bsums, int nb) {
    __shared__ int lds[1024];
    int t = threadIdx.x;
    int v = (t < nb) ? bsums[t] : 0;
    lds[t] = v;
    __syncthreads();
    for (int off = 1; off < 1024; off <<= 1) {
        int x = (t >= off) ? lds[t - off] : 0;
        __syncthreads();
        lds[t] += x;
        __syncthreads();
    }
    if (t < nb) bsums[t] = lds[t] - v;
}

// add chunk offsets in place; extract per-ROW bounds into row_ptr.
__global__ void k_scan3b(int* __restrict__ kpos, const int* __restrict__ bsums,
                         int nk, int ne, int NC, int* __restrict__ row_ptr,
                         int nrows) {
    int i = blockIdx.x * blockDim.x + threadIdx.x;
    if (i < nk) {
        int p = kpos[i] + bsums[i >> 10];
        kpos[i] = p;
        if (i % NC == 0) row_ptr[i / NC] = p;
    }
    if (i == 0) row_ptr[nrows] = ne;
}

// Merged XCD-row-partitioned scatter with (row, colchunk) key.
__global__ void k_scatterk2(const int* __restrict__ rm,
                            const int* __restrict__ cm,
                            const float* __restrict__ vm, int nem,
                            unsigned pmulm, int NCm, unsigned cmulm,
                            int* __restrict__ km, ull* __restrict__ evm,
                            const int* __restrict__ ra,
                            const int* __restrict__ ca,
                            const float* __restrict__ va, int nea,
                            unsigned pmula, int NCa, unsigned cmula,
                            int* __restrict__ ka, ull* __restrict__ eva,
                            int bm) {
    const int p = blockIdx.x & 7;
    const bool is_m = (int)blockIdx.x < bm;
    const int b = is_m ? blockIdx.x : blockIdx.x - bm;
    const int nslot = (is_m ? bm : (int)gridDim.x - bm) >> 3;
    const int bslot = b >> 3;

    const int* rows = is_m ? rm : ra;
    const int* cols = is_m ? cm : ca;
    const float* vals = is_m ? vm : va;
    const int ne = is_m ? nem : nea;
    const unsigned pmul = is_m ? pmulm : pmula;
    const int NC = is_m ? NCm : NCa;
    const unsigned cmul = is_m ? cmulm : cmula;
    int* kpos = is_m ? km : ka;
    ull* ev = is_m ? evm : eva;

    const int nb4 = ne >> 2;
    const v4i* rows4 = (const v4i*)rows;

    for (int g = bslot * blockDim.x + threadIdx.x; g < nb4;
         g += nslot * blockDim.x) {
        v4i r4 = __builtin_nontemporal_load(rows4 + g);
        int base = g << 2;
#pragma unroll
        for (int k = 0; k < 4; ++k) {
            int r = (k == 0) ? r4.x : (k == 1) ? r4.y : (k == 2) ? r4.z : r4.w;
            if ((int)(((unsigned)r * pmul) >> 16) == p) {
                int i = base + k;
                float v = __builtin_nontemporal_load(vals + i);
                int c = __builtin_nontemporal_load(cols + i);
                int key = r * NC + (int)(((unsigned)c * cmul) >> 16);
                ull pk = ((ull)__float_as_uint(v) << 32) | (unsigned)c;
                int pos = atomicAdd(&kpos[key], 1);
                ev[pos] = pk;
            }
        }
    }
    if (bslot == 0 && threadIdx.x == 0) {
        for (int i = nb4 << 2; i < ne; ++i) {
            int r = rows[i];
            if ((int)(((unsigned)r * pmul) >> 16) == p) {
                int c = cols[i];
                int key = r * NC + (int)(((unsigned)c * cmul) >> 16);
                ull pk = ((ull)__float_as_uint(vals[i]) << 32) | (unsigned)c;
                int pos = atomicAdd(&kpos[key], 1);
                ev[pos] = pk;
            }
        }
    }
}

// ----------------------------- fp16 convert --------------------------------

__global__ void k_tohalf(const float* __restrict__ s, _Float16* __restrict__ d,
                         int n) {
    int i = (blockIdx.x * blockDim.x + threadIdx.x) * 4;
    if (i < n) {
        float4 v = *reinterpret_cast<const float4*>(s + i);
        _Float16 h[4] = {(_Float16)v.x, (_Float16)v.y, (_Float16)v.z,
                         (_Float16)v.w};
        *reinterpret_cast<ushort4*>(d + i) = *reinterpret_cast<ushort4*>(h);
    }
}

// ------------------------- quad-edge CSR SpMM ------------------------------
// One wave per row. lane = (q = lane>>4, sub = lane&15). Quarter q processes
// edges with slot%4==q; lane gathers dims (4sub..4sub+3) as one 8B load.
// Row segment is col-chunk-sorted -> gathers L2-concentrate.
template <bool FIRST, bool LAST>
__global__ void k_spmm_quad(const ull* __restrict__ ev,
                            const int* __restrict__ row_ptr,
                            const _Float16* __restrict__ x,
                            _Float16* __restrict__ nxt,
                            float* __restrict__ acc,
                            const float* __restrict__ emb, int nrows) {
    int row = (int)((blockIdx.x * blockDim.x + threadIdx.x) >> 6);
    if (row >= nrows) return;
    int lane = threadIdx.x & 63;
    int q = lane >> 4;
    int sub = lane & 15;

    int s = row_ptr[row];
    int cnt = row_ptr[row + 1] - s;
    const ull* evr = ev + s;

    float a0[UNR], a1[UNR], a2[UNR], a3[UNR];
#pragma unroll
    for (int k = 0; k < UNR; ++k) {
        a0[k] = 0.f; a1[k] = 0.f; a2[k] = 0.f; a3[k] = 0.f;
    }

    int j = 0;
    for (; j + 4 * UNR <= cnt; j += 4 * UNR) {
        ull p[UNR];
#pragma unroll
        for (int k = 0; k < UNR; ++k)
            p[k] = __builtin_nontemporal_load(evr + j + 4 * k + q);
#pragma unroll
        for (int k = 0; k < UNR; ++k) {
            unsigned c = (unsigned)p[k];
            ull xd = *reinterpret_cast<const ull*>(
                x + ((size_t)c << 6) + (sub << 2));
            float v = __uint_as_float((unsigned)(p[k] >> 32));
            union { ull u; _Float16 f[4]; } cv;
            cv.u = xd;
            a0[k] = fmaf(v, (float)cv.f[0], a0[k]);
            a1[k] = fmaf(v, (float)cv.f[1], a1[k]);
            a2[k] = fmaf(v, (float)cv.f[2], a2[k]);
            a3[k] = fmaf(v, (float)cv.f[3], a3[k]);
        }
    }
    if (j < cnt) {
        ull p[UNR];
        bool act[UNR];
#pragma unroll
        for (int k = 0; k < UNR; ++k) {
            int slot = j + 4 * k + q;
            act[k] = slot < cnt;
            p[k] = act[k] ? __builtin_nontemporal_load(evr + slot) : 0ull;
        }
#pragma unroll
        for (int k = 0; k < UNR; ++k) {
            if (act[k]) {
                unsigned c = (unsigned)p[k];
                ull xd = *reinterpret_cast<const ull*>(
                    x + ((size_t)c << 6) + (sub << 2));
                float v = __uint_as_float((unsigned)(p[k] >> 32));
                union { ull u; _Float16 f[4]; } cv;
                cv.u = xd;
                a0[k] = fmaf(v, (float)cv.f[0], a0[k]);
                a1[k] = fmaf(v, (float)cv.f[1], a1[k]);
                a2[k] = fmaf(v, (float)cv.f[2], a2[k]);
                a3[k] = fmaf(v, (float)cv.f[3], a3[k]);
            }
        }
    }
    float t0 = 0.f, t1 = 0.f, t2 = 0.f, t3 = 0.f;
#pragma unroll
    for (int k = 0; k < UNR; ++k) {
        t0 += a0[k]; t1 += a1[k]; t2 += a2[k]; t3 += a3[k];
    }
    t0 += __shfl_xor(t0, 16); t0 += __shfl_xor(t0, 32);
    t1 += __shfl_xor(t1, 16); t1 += __shfl_xor(t1, 32);
    t2 += __shfl_xor(t2, 16); t2 += __shfl_xor(t2, 32);
    t3 += __shfl_xor(t3, 16); t3 += __shfl_xor(t3, 32);

    size_t base = ((size_t)row << 6) + (sub << 2);
    if (FIRST || !LAST) {
        if (q == 0) {
            float4 prev;
            if (FIRST)
                prev = *reinterpret_cast<const float4*>(emb + base);
            else
                prev = *reinterpret_cast<const float4*>(acc + base);
            float4 o = make_float4(prev.x + t0, prev.y + t1, prev.z + t2,
                                   prev.w + t3);
            *reinterpret_cast<float4*>(acc + base) = o;
            union { _Float16 f[4]; ull u; } h;
            h.f[0] = (_Float16)t0; h.f[1] = (_Float16)t1;
            h.f[2] = (_Float16)t2; h.f[3] = (_Float16)t3;
            *reinterpret_cast<ull*>(nxt + base) = h.u;
        }
    } else {
        float4 a2v = *reinterpret_cast<const float4*>(acc + base);
        float b0 = (a2v.x + t0) * 0.25f;
        float b1 = (a2v.y + t1) * 0.25f;
        float b2 = (a2v.z + t2) * 0.25f;
        float b3 = (a2v.w + t3) * 0.25f;
        float ss = b0 * b0 + b1 * b1 + b2 * b2 + b3 * b3;
#pragma unroll
        for (int off = 8; off; off >>= 1) ss += __shfl_xor(ss, off);
        float nrm = fmaxf(sqrtf(ss), 1e-12f);
        if (q == 0) {
            float4 o = make_float4(b0 / nrm, b1 / nrm, b2 / nrm, b3 / nrm);
            *reinterpret_cast<float4*>(acc + base) = o;
        }
    }
}

// ----------------------- fallback: atomic path -----------------------------

__global__ void k_copy2(const float4* __restrict__ src, float4* __restrict__ a,
                        float4* __restrict__ b, int n4) {
    int i = blockIdx.x * blockDim.x + threadIdx.x;
    if (i < n4) {
        float4 v = src[i];
        a[i] = v;
        b[i] = v;
    }
}

__global__ void k_zero(float4* __restrict__ p, int n4) {
    int i = blockIdx.x * blockDim.x + threadIdx.x;
    if (i < n4) p[i] = make_float4(0.f, 0.f, 0.f, 0.f);
}

__global__ void k_axpy(float4* __restrict__ acc, const float4* __restrict__ x,
                       int n4) {
    int i = blockIdx.x * blockDim.x + threadIdx.x;
    if (i < n4) {
        float4 a = acc[i];
        float4 v = x[i];
        a.x += v.x; a.y += v.y; a.z += v.z; a.w += v.w;
        acc[i] = a;
    }
}

__global__ void k_spmm_atomic(const int* __restrict__ rows,
                              const int* __restrict__ cols,
                              const float* __restrict__ vals,
                              const float* __restrict__ x,
                              float* __restrict__ y, int n_edges) {
    unsigned tid = blockIdx.x * blockDim.x + threadIdx.x;
    unsigned e = tid >> 4;
    if (e >= (unsigned)n_edges) return;
    int sub = tid & 15;
    int r = rows[e];
    int c = cols[e];
    float v = vals[e];
    const float4 xv =
        *reinterpret_cast<const float4*>(x + ((size_t)c << 6) + (sub << 2));
    float* yp = y + ((size_t)r << 6) + (sub << 2);
    unsafeAtomicAdd(yp + 0, v * xv.x);
    unsafeAtomicAdd(yp + 1, v * xv.y);
    unsafeAtomicAdd(yp + 2, v * xv.z);
    unsafeAtomicAdd(yp + 3, v * xv.w);
}

__global__ void k_normalize(float* __restrict__ out, int nrows) {
    int row = blockIdx.x * 4 + (threadIdx.x >> 6);
    if (row >= nrows) return;
    int lane = threadIdx.x & 63;
    size_t idx = ((size_t)row << 6) + lane;
    float v = out[idx] * 0.25f;
    float s = v * v;
#pragma unroll
    for (int off = 32; off; off >>= 1) s += __shfl_xor(s, off);
    float norm = fmaxf(sqrtf(s), 1e-12f);
    out[idx] = v / norm;
}

// ---------------------------------------------------------------------------

extern "C" void kernel_launch(void* const* d_in, const int* in_sizes, int n_in,
                              void* d_out, int out_size, void* d_ws,
                              size_t ws_size, hipStream_t stream) {
    const int* m_rows = (const int*)d_in[0];
    const int* m_cols = (const int*)d_in[1];
    const float* m_vals = (const float*)d_in[2];
    const int* a_rows = (const int*)d_in[3];
    const int* a_cols = (const int*)d_in[4];
    const float* a_vals = (const float*)d_in[5];
    const float* m_emb = (const float*)d_in[6];
    const float* a_emb = (const float*)d_in[7];

    int ne_m = in_sizes[0];
    int ne_a = in_sizes[3];
    int nm = in_sizes[6] / EMB_DIM;
    int na = in_sizes[7] / EMB_DIM;

    size_t elems_m = (size_t)nm * EMB_DIM;
    int nmax = nm > na ? nm : na;
    float* out_m = (float*)d_out;
    float* out_a = out_m + elems_m;

    // chunk counts: fp16 x-slice target ~2MB
    int NC_m = cdiv((long long)nm * 2 * EMB_DIM, 2097152);
    int NC_a = cdiv((long long)na * 2 * EMB_DIM, 2097152);
    if (NC_m < 1) NC_m = 1;
    if (NC_a < 1) NC_a = 1;
    int nk_m = nm * NC_m;
    int nk_a = na * NC_a;

    // ws layout: ev_m + ev_a + x0h + buf0h + row_ptrs. kpos/bsums alias buf0h
    // (build completes before any SpMM writes buf0h).
    char* w = (char*)d_ws;
    ull* ev_m = (ull*)w;            w += (size_t)ne_m * sizeof(ull);
    ull* ev_a = (ull*)w;            w += (size_t)ne_a * sizeof(ull);
    _Float16* x0h = (_Float16*)w;   w += (size_t)nmax * EMB_DIM * sizeof(_Float16);
    _Float16* buf0h = (_Float16*)w; w += (size_t)nmax * EMB_DIM * sizeof(_Float16);
    int* row_ptr_m = (int*)w;       w += ((size_t)nm + 1) * sizeof(int);
    int* row_ptr_a = (int*)w;       w += ((size_t)na + 1) * sizeof(int);
    size_t need = (size_t)(w - (char*)d_ws);

    // aliases inside buf0h (need (nk_m+nk_a+1024)*4 <= nmax*128 bytes)
    int* kpos_m = (int*)buf0h;
    int* kpos_a = kpos_m + nk_m;
    int* bsums = kpos_a + nk_a;
    bool alias_ok =
        ((size_t)nk_m + nk_a + 1024) * sizeof(int) <= (size_t)nmax * EMB_DIM * 2;

    if (ws_size >= need && alias_ok) {
        unsigned cmul_m = (unsigned)(((unsigned long long)NC_m << 16) / (unsigned)nm);
        unsigned cmul_a = (unsigned)(((unsigned long long)NC_a << 16) / (unsigned)na);
        unsigned pmul_m = (unsigned)(((unsigned long long)8 << 16) / (unsigned)nm);
        unsigned pmul_a = (unsigned)(((unsigned long long)8 << 16) / (unsigned)na);

        // ---- merged CSR build (col-chunk keys) ----
        k_zero_i<<<cdiv(nk_m + nk_a, 256), 256, 0, stream>>>(kpos_m,
                                                             nk_m + nk_a);
        k_histk2<<<cdiv((ne_m >> 2) + (ne_a >> 2) + 1, 256), 256, 0, stream>>>(
            m_rows, m_cols, ne_m, NC_m, cmul_m, kpos_m, a_rows, a_cols, ne_a,
            NC_a, cmul_a, kpos_a);
        int nsb_m = cdiv(nk_m, SCAN_E);
        k_scan1<<<nsb_m, SCAN_B, 0, stream>>>(kpos_m, nk_m, kpos_m, bsums);
        k_scan2<<<1, 1024, 0, stream>>>(bsums, nsb_m);
        k_scan3b<<<cdiv(nk_m, 256), 256, 0, stream>>>(kpos_m, bsums, nk_m,
                                                      ne_m, NC_m, row_ptr_m,
                                                      nm);
        int nsb_a = cdiv(nk_a, SCAN_E);
        k_scan1<<<nsb_a, SCAN_B, 0, stream>>>(kpos_a, nk_a, kpos_a, bsums);
        k_scan2<<<1, 1024, 0, stream>>>(bsums, nsb_a);
        k_scan3b<<<cdiv(nk_a, 256), 256, 0, stream>>>(kpos_a, bsums, nk_a,
                                                      ne_a, NC_a, row_ptr_a,
                                                      na);
        k_scatterk2<<<2048, 256, 0, stream>>>(
            m_rows, m_cols, m_vals, ne_m, pmul_m, NC_m, cmul_m, kpos_m, ev_m,
            a_rows, a_cols, a_vals, ne_a, pmul_a, NC_a, cmul_a, kpos_a, ev_a,
            1408);

        auto run_spmm = [&](ull* ev, int* row_ptr, const float* emb,
                            float* out, int n) {
            int nel = n * EMB_DIM;
            k_tohalf<<<cdiv(nel / 4, 256), 256, 0, stream>>>(emb, x0h, nel);
            int g = cdiv(n, 4);
            k_spmm_quad<true, false><<<g, 256, 0, stream>>>(
                ev, row_ptr, x0h, buf0h, out, emb, n);
            k_spmm_quad<false, false><<<g, 256, 0, stream>>>(
                ev, row_ptr, buf0h, x0h, out, nullptr, n);
            k_spmm_quad<false, true><<<g, 256, 0, stream>>>(
                ev, row_ptr, x0h, nullptr, out, nullptr, n);
        };
        run_spmm(ev_m, row_ptr_m, m_emb, out_m, nm);
        run_spmm(ev_a, row_ptr_a, a_emb, out_a, na);
        return;
    }

    // Fallback: round-0 atomic path.
    float* fb0 = (float*)d_ws;
    float* fb1 = fb0 + elems_m;
    auto run_atomic = [&](const int* rows, const int* cols, const float* vals,
                          const float* emb, float* out, int nrows,
                          int nedges) {
        size_t n = (size_t)nrows * EMB_DIM;
        int n4 = (int)(n / 4);
        int eg = cdiv(n4, 256);
        k_copy2<<<eg, 256, 0, stream>>>((const float4*)emb, (float4*)out,
                                        (float4*)fb0, n4);
        float* cur = fb0;
        float* nxt = fb1;
        int spmm_grid = cdiv((long long)nedges * 16, 256);
        for (int l = 0; l < 3; ++l) {
            k_zero<<<eg, 256, 0, stream>>>((float4*)nxt, n4);
            k_spmm_atomic<<<spmm_grid, 256, 0, stream>>>(rows, cols, vals, cur,
                                                         nxt, nedges);
            k_axpy<<<eg, 256, 0, stream>>>((float4*)out, (const float4*)nxt,
                                           n4);
            float* t = cur; cur = nxt; nxt = t;
        }
        k_normalize<<<cdiv(nrows, 4), 256, 0, stream>>>(out, nrows);
    };
    run_atomic(m_rows, m_cols, m_vals, m_emb, out_m, nm, ne_m);
    run_atomic(a_rows, a_cols, a_vals, a_emb, out_a, na, ne_a);
}

// Round 10
// 950.825 us; speedup vs baseline: 1.0364x; 1.0364x over previous
//
#include <hip/hip_runtime.h>

// ---------------------------------------------------------------------------
// LightGCN propagation: out = normalize(mean(emb, A emb, A^2 emb, A^3 emb))
// for two graphs (mashup: 100k nodes / 3.2M edges, api: 50k / 1.6M), D=64.
//
// Round-9 = round-7 structure (plain row-key CSR; col-chunk keys reverted:
// rows are ~1 loop iteration long, intra-row order is irrelevant) with
// FULL TWO-GRAPH DISPATCH MERGING:
//  - one dispatch each for zero/hist/scan1/scan2/scan3/scatter/tohalf
//  - one dispatch PER LAYER for the SpMM (grid = nm+na rows); api rows fill
//    the mashup dispatch's drain tail.
//  - both graphs' fp16 ping-pong buffers resident (ws 77.40MB < proven
//    77.60MB); row_pos/bsums alias x0h_m (dead until after scatter).
//  - quad-edge SpMM unchanged from r7 (LLC-BW-bound at ~3 TB/s).
// ---------------------------------------------------------------------------

#define EMB_DIM 64
#define UNR 8
typedef unsigned long long ull;
typedef int v4i __attribute__((ext_vector_type(4)));

static inline int cdiv(long long a, long long b) { return (int)((a + b - 1) / b); }

// ----------------------------- CSR build -----------------------------------

__global__ void k_zero2(int* __restrict__ pm, int nm_, int* __restrict__ pa,
                        int na_) {
    int i = blockIdx.x * blockDim.x + threadIdx.x;
    if (i < nm_) pm[i] = 0;
    else if (i < nm_ + na_) pa[i - nm_] = 0;
}

// merged vectorized histogram: 4 edges per thread.
__global__ void k_hist2(const int* __restrict__ rm, int nem,
                        int* __restrict__ posm, const int* __restrict__ ra,
                        int nea, int* __restrict__ posa) {
    int nm4 = nem >> 2, na4 = nea >> 2;
    int i = blockIdx.x * blockDim.x + threadIdx.x;
    if (i < nm4) {
        v4i r = __builtin_nontemporal_load((const v4i*)rm + i);
        atomicAdd(&posm[r.x], 1);
        atomicAdd(&posm[r.y], 1);
        atomicAdd(&posm[r.z], 1);
        atomicAdd(&posm[r.w], 1);
    } else if (i < nm4 + na4) {
        v4i r = __builtin_nontemporal_load((const v4i*)ra + (i - nm4));
        atomicAdd(&posa[r.x], 1);
        atomicAdd(&posa[r.y], 1);
        atomicAdd(&posa[r.z], 1);
        atomicAdd(&posa[r.w], 1);
    } else if (i == nm4 + na4) {
        for (int t = nm4 << 2; t < nem; ++t) atomicAdd(&posm[rm[t]], 1);
        for (int t = na4 << 2; t < nea; ++t) atomicAdd(&posa[ra[t]], 1);
    }
}

#define SCAN_B 256
#define SCAN_E 1024

// merged phase-1 scan: blocks [0,nsbm) -> graph m, rest -> graph a.
__global__ void k_scan1m(const int* __restrict__ inm, int nm_,
                         int* __restrict__ outm, int* __restrict__ bsm,
                         int nsbm, const int* __restrict__ ina, int na_,
                         int* __restrict__ outa, int* __restrict__ bsa) {
    bool is_m = (int)blockIdx.x < nsbm;
    const int* in = is_m ? inm : ina;
    int* out = is_m ? outm : outa;
    int* bsums = is_m ? bsm : bsa;
    int n = is_m ? nm_ : na_;
    int b = is_m ? blockIdx.x : blockIdx.x - nsbm;

    __shared__ int lds[SCAN_B];
    int t = threadIdx.x;
    int base = b * SCAN_E + t * 4;
    int v[4];
    int s = 0;
#pragma unroll
    for (int j = 0; j < 4; ++j) {
        v[j] = (base + j < n) ? in[base + j] : 0;
        s += v[j];
    }
    lds[t] = s;
    __syncthreads();
    for (int off = 1; off < SCAN_B; off <<= 1) {
        int x = (t >= off) ? lds[t - off] : 0;
        __syncthreads();
        lds[t] += x;
        __syncthreads();
    }
    int run = lds[t] - s;
    if (t == SCAN_B - 1) bsums[b] = lds[t];
#pragma unroll
    for (int j = 0; j < 4; ++j) {
        if (base + j < n) out[base + j] = run;
        run += v[j];
    }
}

// merged phase-2: block 0 scans bsums_m, block 1 scans bsums_a.
__global__ void k_scan2m(int* __restrict__ bsm, int nbm, int* __restrict__ bsa,
                         int nba) {
    int* bsums = (blockIdx.x == 0) ? bsm : bsa;
    int nb = (blockIdx.x == 0) ? nbm : nba;
    __shared__ int lds[1024];
    int t = threadIdx.x;
    int v = (t < nb) ? bsums[t] : 0;
    lds[t] = v;
    __syncthreads();
    for (int off = 1; off < 1024; off <<= 1) {
        int x = (t >= off) ? lds[t - off] : 0;
        __syncthreads();
        lds[t] += x;
        __syncthreads();
    }
    if (t < nb) bsums[t] = lds[t] - v;
}

// merged phase-3: add chunk offsets, copy cursors, cap row_ptr[n].
__global__ void k_scan3m(int* __restrict__ rpm, int* __restrict__ posm,
                         const int* __restrict__ bsm, int nm_, int nem,
                         int* __restrict__ rpa, int* __restrict__ posa,
                         const int* __restrict__ bsa, int na_, int nea) {
    int i = blockIdx.x * blockDim.x + threadIdx.x;
    if (i < nm_) {
        int p = rpm[i] + bsm[i >> 10];
        rpm[i] = p;
        posm[i] = p;
        if (i == 0) rpm[nm_] = nem;
    } else if (i < nm_ + na_) {
        int ii = i - nm_;
        int p = rpa[ii] + bsa[ii >> 10];
        rpa[ii] = p;
        posa[ii] = p;
        if (ii == 0) rpa[na_] = nea;
    }
}

// Merged XCD-partitioned scatter: blocks [0,bm) -> mashup, [bm,grid) -> api.
__global__ void k_scatter2(const int* __restrict__ rm,
                           const int* __restrict__ cm,
                           const float* __restrict__ vm, int nem,
                           unsigned pmulm, int* __restrict__ posm,
                           ull* __restrict__ evm, const int* __restrict__ ra,
                           const int* __restrict__ ca,
                           const float* __restrict__ va, int nea,
                           unsigned pmula, int* __restrict__ posa,
                           ull* __restrict__ eva, int bm) {
    const int p = blockIdx.x & 7;
    const bool is_m = (int)blockIdx.x < bm;
    const int b = is_m ? blockIdx.x : blockIdx.x - bm;
    const int nslot = (is_m ? bm : (int)gridDim.x - bm) >> 3;
    const int bslot = b >> 3;

    const int* rows = is_m ? rm : ra;
    const int* cols = is_m ? cm : ca;
    const float* vals = is_m ? vm : va;
    const int ne = is_m ? nem : nea;
    const unsigned pmul = is_m ? pmulm : pmula;
    int* row_pos = is_m ? posm : posa;
    ull* ev = is_m ? evm : eva;

    const int nb4 = ne >> 2;
    const v4i* rows4 = (const v4i*)rows;

    for (int g = bslot * blockDim.x + threadIdx.x; g < nb4;
         g += nslot * blockDim.x) {
        v4i r4 = __builtin_nontemporal_load(rows4 + g);
        int base = g << 2;
#pragma unroll
        for (int k = 0; k < 4; ++k) {
            int r = (k == 0) ? r4.x : (k == 1) ? r4.y : (k == 2) ? r4.z : r4.w;
            if ((int)(((unsigned)r * pmul) >> 16) == p) {
                int i = base + k;
                float v = __builtin_nontemporal_load(vals + i);
                int c = __builtin_nontemporal_load(cols + i);
                ull pk = ((ull)__float_as_uint(v) << 32) | (unsigned)c;
                int pos = atomicAdd(&row_pos[r], 1);
                ev[pos] = pk;
            }
        }
    }
    if (bslot == 0 && threadIdx.x == 0) {
        for (int i = nb4 << 2; i < ne; ++i) {
            int r = rows[i];
            if ((int)(((unsigned)r * pmul) >> 16) == p) {
                ull pk = ((ull)__float_as_uint(vals[i]) << 32) |
                         (unsigned)cols[i];
                int pos = atomicAdd(&row_pos[r], 1);
                ev[pos] = pk;
            }
        }
    }
}

// ------------------------ merged fp16 convert ------------------------------

__global__ void k_tohalf2(const float* __restrict__ sm, _Float16* __restrict__ dm,
                          int nm4, const float* __restrict__ sa,
                          _Float16* __restrict__ da, int na4) {
    int i = blockIdx.x * blockDim.x + threadIdx.x;
    const float* s;
    _Float16* d;
    int j;
    if (i < nm4) {
        s = sm; d = dm; j = i;
    } else if (i < nm4 + na4) {
        s = sa; d = da; j = i - nm4;
    } else {
        return;
    }
    float4 v = *reinterpret_cast<const float4*>(s + j * 4);
    _Float16 h[4] = {(_Float16)v.x, (_Float16)v.y, (_Float16)v.z,
                     (_Float16)v.w};
    *reinterpret_cast<ushort4*>(d + j * 4) = *reinterpret_cast<ushort4*>(h);
}

// ------------------------- quad-edge CSR SpMM ------------------------------
// One wave per row. lane = (q = lane>>4, sub = lane&15). Quarter q processes
// edges with slot%4==q; lane gathers dims (4sub..4sub+3) as one 8B load.
template <bool FIRST, bool LAST>
__device__ __forceinline__ void spmm_row(const ull* __restrict__ ev,
                                         const int* __restrict__ row_ptr,
                                         const _Float16* __restrict__ x,
                                         _Float16* __restrict__ nxt,
                                         float* __restrict__ acc,
                                         const float* __restrict__ emb,
                                         int row, int lane) {
    int q = lane >> 4;
    int sub = lane & 15;

    int s = row_ptr[row];
    int cnt = row_ptr[row + 1] - s;
    const ull* evr = ev + s;

    float a0[UNR], a1[UNR], a2[UNR], a3[UNR];
#pragma unroll
    for (int k = 0; k < UNR; ++k) {
        a0[k] = 0.f; a1[k] = 0.f; a2[k] = 0.f; a3[k] = 0.f;
    }

    int j = 0;
    for (; j + 4 * UNR <= cnt; j += 4 * UNR) {
        ull p[UNR];
#pragma unroll
        for (int k = 0; k < UNR; ++k)
            p[k] = __builtin_nontemporal_load(evr + j + 4 * k + q);
#pragma unroll
        for (int k = 0; k < UNR; ++k) {
            unsigned c = (unsigned)p[k];
            ull xd = *reinterpret_cast<const ull*>(
                x + ((size_t)c << 6) + (sub << 2));
            float v = __uint_as_float((unsigned)(p[k] >> 32));
            union { ull u; _Float16 f[4]; } cv;
            cv.u = xd;
            a0[k] = fmaf(v, (float)cv.f[0], a0[k]);
            a1[k] = fmaf(v, (float)cv.f[1], a1[k]);
            a2[k] = fmaf(v, (float)cv.f[2], a2[k]);
            a3[k] = fmaf(v, (float)cv.f[3], a3[k]);
        }
    }
    if (j < cnt) {
        ull p[UNR];
        bool act[UNR];
#pragma unroll
        for (int k = 0; k < UNR; ++k) {
            int slot = j + 4 * k + q;
            act[k] = slot < cnt;
            p[k] = act[k] ? __builtin_nontemporal_load(evr + slot) : 0ull;
        }
#pragma unroll
        for (int k = 0; k < UNR; ++k) {
            if (act[k]) {
                unsigned c = (unsigned)p[k];
                ull xd = *reinterpret_cast<const ull*>(
                    x + ((size_t)c << 6) + (sub << 2));
                float v = __uint_as_float((unsigned)(p[k] >> 32));
                union { ull u; _Float16 f[4]; } cv;
                cv.u = xd;
                a0[k] = fmaf(v, (float)cv.f[0], a0[k]);
                a1[k] = fmaf(v, (float)cv.f[1], a1[k]);
                a2[k] = fmaf(v, (float)cv.f[2], a2[k]);
                a3[k] = fmaf(v, (float)cv.f[3], a3[k]);
            }
        }
    }
    float t0 = 0.f, t1 = 0.f, t2 = 0.f, t3 = 0.f;
#pragma unroll
    for (int k = 0; k < UNR; ++k) {
        t0 += a0[k]; t1 += a1[k]; t2 += a2[k]; t3 += a3[k];
    }
    t0 += __shfl_xor(t0, 16); t0 += __shfl_xor(t0, 32);
    t1 += __shfl_xor(t1, 16); t1 += __shfl_xor(t1, 32);
    t2 += __shfl_xor(t2, 16); t2 += __shfl_xor(t2, 32);
    t3 += __shfl_xor(t3, 16); t3 += __shfl_xor(t3, 32);

    size_t base = ((size_t)row << 6) + (sub << 2);
    if (FIRST || !LAST) {
        if (q == 0) {
            float4 prev;
            if (FIRST)
                prev = *reinterpret_cast<const float4*>(emb + base);
            else
                prev = *reinterpret_cast<const float4*>(acc + base);
            float4 o = make_float4(prev.x + t0, prev.y + t1, prev.z + t2,
                                   prev.w + t3);
            *reinterpret_cast<float4*>(acc + base) = o;
            union { _Float16 f[4]; ull u; } h;
            h.f[0] = (_Float16)t0; h.f[1] = (_Float16)t1;
            h.f[2] = (_Float16)t2; h.f[3] = (_Float16)t3;
            *reinterpret_cast<ull*>(nxt + base) = h.u;
        }
    } else {
        float4 a2v = *reinterpret_cast<const float4*>(acc + base);
        float b0 = (a2v.x + t0) * 0.25f;
        float b1 = (a2v.y + t1) * 0.25f;
        float b2 = (a2v.z + t2) * 0.25f;
        float b3 = (a2v.w + t3) * 0.25f;
        float ss = b0 * b0 + b1 * b1 + b2 * b2 + b3 * b3;
#pragma unroll
        for (int off = 8; off; off >>= 1) ss += __shfl_xor(ss, off);
        float nrm = fmaxf(sqrtf(ss), 1e-12f);
        if (q == 0) {
            float4 o = make_float4(b0 / nrm, b1 / nrm, b2 / nrm, b3 / nrm);
            *reinterpret_cast<float4*>(acc + base) = o;
        }
    }
}

// merged two-graph SpMM: waves [0,nm) -> mashup rows, [nm,nm+na) -> api rows.
template <bool FIRST, bool LAST>
__global__ void k_spmm2(const ull* __restrict__ evm,
                        const int* __restrict__ rpm,
                        const _Float16* __restrict__ xm,
                        _Float16* __restrict__ nxm, float* __restrict__ accm,
                        const float* __restrict__ embm, int nm_,
                        const ull* __restrict__ eva,
                        const int* __restrict__ rpa,
                        const _Float16* __restrict__ xa,
                        _Float16* __restrict__ nxa, float* __restrict__ acca,
                        const float* __restrict__ emba, int na_) {
    int wid = (int)((blockIdx.x * blockDim.x + threadIdx.x) >> 6);
    int lane = threadIdx.x & 63;
    if (wid < nm_) {
        spmm_row<FIRST, LAST>(evm, rpm, xm, nxm, accm, embm, wid, lane);
    } else if (wid < nm_ + na_) {
        spmm_row<FIRST, LAST>(eva, rpa, xa, nxa, acca, emba, wid - nm_, lane);
    }
}

// ----------------------- fallback: atomic path -----------------------------

__global__ void k_copy2(const float4* __restrict__ src, float4* __restrict__ a,
                        float4* __restrict__ b, int n4) {
    int i = blockIdx.x * blockDim.x + threadIdx.x;
    if (i < n4) {
        float4 v = src[i];
        a[i] = v;
        b[i] = v;
    }
}

__global__ void k_zero(float4* __restrict__ p, int n4) {
    int i = blockIdx.x * blockDim.x + threadIdx.x;
    if (i < n4) p[i] = make_float4(0.f, 0.f, 0.f, 0.f);
}

__global__ void k_axpy(float4* __restrict__ acc, const float4* __restrict__ x,
                       int n4) {
    int i = blockIdx.x * blockDim.x + threadIdx.x;
    if (i < n4) {
        float4 a = acc[i];
        float4 v = x[i];
        a.x += v.x; a.y += v.y; a.z += v.z; a.w += v.w;
        acc[i] = a;
    }
}

__global__ void k_spmm_atomic(const int* __restrict__ rows,
                              const int* __restrict__ cols,
                              const float* __restrict__ vals,
                              const float* __restrict__ x,
                              float* __restrict__ y, int n_edges) {
    unsigned tid = blockIdx.x * blockDim.x + threadIdx.x;
    unsigned e = tid >> 4;
    if (e >= (unsigned)n_edges) return;
    int sub = tid & 15;
    int r = rows[e];
    int c = cols[e];
    float v = vals[e];
    const float4 xv =
        *reinterpret_cast<const float4*>(x + ((size_t)c << 6) + (sub << 2));
    float* yp = y + ((size_t)r << 6) + (sub << 2);
    unsafeAtomicAdd(yp + 0, v * xv.x);
    unsafeAtomicAdd(yp + 1, v * xv.y);
    unsafeAtomicAdd(yp + 2, v * xv.z);
    unsafeAtomicAdd(yp + 3, v * xv.w);
}

__global__ void k_normalize(float* __restrict__ out, int nrows) {
    int row = blockIdx.x * 4 + (threadIdx.x >> 6);
    if (row >= nrows) return;
    int lane = threadIdx.x & 63;
    size_t idx = ((size_t)row << 6) + lane;
    float v = out[idx] * 0.25f;
    float s = v * v;
#pragma unroll
    for (int off = 32; off; off >>= 1) s += __shfl_xor(s, off);
    float norm = fmaxf(sqrtf(s), 1e-12f);
    out[idx] = v / norm;
}

// ---------------------------------------------------------------------------

extern "C" void kernel_launch(void* const* d_in, const int* in_sizes, int n_in,
                              void* d_out, int out_size, void* d_ws,
                              size_t ws_size, hipStream_t stream) {
    const int* m_rows = (const int*)d_in[0];
    const int* m_cols = (const int*)d_in[1];
    const float* m_vals = (const float*)d_in[2];
    const int* a_rows = (const int*)d_in[3];
    const int* a_cols = (const int*)d_in[4];
    const float* a_vals = (const float*)d_in[5];
    const float* m_emb = (const float*)d_in[6];
    const float* a_emb = (const float*)d_in[7];

    int ne_m = in_sizes[0];
    int ne_a = in_sizes[3];
    int nm = in_sizes[6] / EMB_DIM;
    int na = in_sizes[7] / EMB_DIM;

    size_t elems_m = (size_t)nm * EMB_DIM;
    size_t elems_a = (size_t)na * EMB_DIM;
    float* out_m = (float*)d_out;
    float* out_a = out_m + elems_m;

    // ws layout: both graphs' ev + fp16 ping-pongs resident (77.4MB).
    char* w = (char*)d_ws;
    ull* ev_m = (ull*)w;            w += (size_t)ne_m * sizeof(ull);
    ull* ev_a = (ull*)w;            w += (size_t)ne_a * sizeof(ull);
    _Float16* x0h_m = (_Float16*)w; w += elems_m * sizeof(_Float16);
    _Float16* buf_m = (_Float16*)w; w += elems_m * sizeof(_Float16);
    _Float16* x0h_a = (_Float16*)w; w += elems_a * sizeof(_Float16);
    _Float16* buf_a = (_Float16*)w; w += elems_a * sizeof(_Float16);
    int* row_ptr_m = (int*)w;       w += ((size_t)nm + 1) * sizeof(int);
    int* row_ptr_a = (int*)w;       w += ((size_t)na + 1) * sizeof(int);
    size_t need = (size_t)(w - (char*)d_ws);

    // aliases inside x0h_m region (dead until after scatter; tohalf runs later)
    int* row_pos_m = (int*)x0h_m;
    int* row_pos_a = row_pos_m + nm;
    int* bsums_m = row_pos_a + na;
    int* bsums_a = bsums_m + 1024;
    bool alias_ok = ((size_t)nm + na + 2048) * sizeof(int) <=
                    elems_m * sizeof(_Float16);

    if (ws_size >= need && alias_ok) {
        // ---- merged CSR build ----
        k_zero2<<<cdiv(nm + na, 256), 256, 0, stream>>>(row_pos_m, nm,
                                                        row_pos_a, na);
        k_hist2<<<cdiv((ne_m >> 2) + (ne_a >> 2) + 1, 256), 256, 0, stream>>>(
            m_rows, ne_m, row_pos_m, a_rows, ne_a, row_pos_a);
        int nsb_m = cdiv(nm, SCAN_E);
        int nsb_a = cdiv(na, SCAN_E);
        k_scan1m<<<nsb_m + nsb_a, SCAN_B, 0, stream>>>(
            row_pos_m, nm, row_ptr_m, bsums_m, nsb_m, row_pos_a, na,
            row_ptr_a, bsums_a);
        k_scan2m<<<2, 1024, 0, stream>>>(bsums_m, nsb_m, bsums_a, nsb_a);
        k_scan3m<<<cdiv(nm + na, 256), 256, 0, stream>>>(
            row_ptr_m, row_pos_m, bsums_m, nm, ne_m, row_ptr_a, row_pos_a,
            bsums_a, na, ne_a);
        unsigned pmul_m = (unsigned)(((unsigned long long)8 << 16) / (unsigned)nm);
        unsigned pmul_a = (unsigned)(((unsigned long long)8 << 16) / (unsigned)na);
        k_scatter2<<<2048, 256, 0, stream>>>(m_rows, m_cols, m_vals, ne_m,
                                             pmul_m, row_pos_m, ev_m, a_rows,
                                             a_cols, a_vals, ne_a, pmul_a,
                                             row_pos_a, ev_a, 1408);
        // ---- merged fp16 source (overwrites row_pos/bsums aliases) ----
        int nm4 = (int)(elems_m / 4), na4 = (int)(elems_a / 4);
        k_tohalf2<<<cdiv(nm4 + na4, 256), 256, 0, stream>>>(
            m_emb, x0h_m, nm4, a_emb, x0h_a, na4);
        // ---- 3 merged SpMM layers (ping-pong per graph) ----
        int g = cdiv(nm + na, 4);
        k_spmm2<true, false><<<g, 256, 0, stream>>>(
            ev_m, row_ptr_m, x0h_m, buf_m, out_m, m_emb, nm,
            ev_a, row_ptr_a, x0h_a, buf_a, out_a, a_emb, na);
        k_spmm2<false, false><<<g, 256, 0, stream>>>(
            ev_m, row_ptr_m, buf_m, x0h_m, out_m, nullptr, nm,
            ev_a, row_ptr_a, buf_a, x0h_a, out_a, nullptr, na);
        k_spmm2<false, true><<<g, 256, 0, stream>>>(
            ev_m, row_ptr_m, x0h_m, nullptr, out_m, nullptr, nm,
            ev_a, row_ptr_a, x0h_a, nullptr, out_a, nullptr, na);
        return;
    }

    // Fallback: round-0 atomic path.
    float* fb0 = (float*)d_ws;
    float* fb1 = fb0 + elems_m;
    auto run_atomic = [&](const int* rows, const int* cols, const float* vals,
                          const float* emb, float* out, int nrows,
                          int nedges) {
        size_t n = (size_t)nrows * EMB_DIM;
        int n4 = (int)(n / 4);
        int eg = cdiv(n4, 256);
        k_copy2<<<eg, 256, 0, stream>>>((const float4*)emb, (float4*)out,
                                        (float4*)fb0, n4);
        float* cur = fb0;
        float* nxt = fb1;
        int spmm_grid = cdiv((long long)nedges * 16, 256);
        for (int l = 0; l < 3; ++l) {
            k_zero<<<eg, 256, 0, stream>>>((float4*)nxt, n4);
            k_spmm_atomic<<<spmm_grid, 256, 0, stream>>>(rows, cols, vals, cur,
                                                         nxt, nedges);
            k_axpy<<<eg, 256, 0, stream>>>((float4*)out, (const float4*)nxt,
                                           n4);
            float* t = cur; cur = nxt; nxt = t;
        }
        k_normalize<<<cdiv(nrows, 4), 256, 0, stream>>>(out, nrows);
    };
    run_atomic(m_rows, m_cols, m_vals, m_emb, out_m, nm, ne_m);
    run_atomic(a_rows, a_cols, a_vals, a_emb, out_a, na, ne_a);
}